// Round 2
// baseline (278.895 us; speedup 1.0000x reference)
//
#include <hip/hip_runtime.h>

// Volume-rendering composite: B=65536 rays, N=128 samples/ray.
//   w_i = exp(-S_i) - exp(-S_{i+1}),  S_i = prefix sum of sigma*delta
// Outputs per ray: rgb(3) | depth(1) | normal(3) | acc(1) -> [B, 8] f32
//
// R2 structure: 2 rays per wave (32 lanes/ray), 4 samples/lane.
//  - density/deltas/zs: one float4 per lane -> 64x16B = 1KB contiguous per
//    instruction (perfect coalescing, 2 scalar rows per wave).
//  - prefix scan + 8 reductions done entirely with DPP VALU adds
//    (row_shr:1/2/4/8 + row_bcast:15) -- no LDS-pipe ds_bpermute latency.
//  - lanes 31/63 hold their ray's totals after the inclusive DPP scan and
//    write the 8 outputs directly.

constexpr int RAYS = 65536;
constexpr int NS   = 128;

// x += dpp_shifted(x); invalid source lanes contribute 0 (old=0, bound_ctrl).
#define DPP_ADD(x, ctrl, rm)                                                   \
    x += __int_as_float(__builtin_amdgcn_update_dpp(                           \
        0, __float_as_int(x), ctrl, rm, 0xf, true))

// Inclusive prefix sum over each 32-lane half (rows 0..1 and rows 2..3).
// row_shr:1=0x111, :2=0x112, :4=0x114, :8=0x118, row_bcast:15=0x142.
// row_mask 0xa = rows 1,3 -> bcast15 only crosses 0->1 and 2->3 (stays in half).
__device__ __forceinline__ float scan32(float x) {
    DPP_ADD(x, 0x111, 0xf);
    DPP_ADD(x, 0x112, 0xf);
    DPP_ADD(x, 0x114, 0xf);
    DPP_ADD(x, 0x118, 0xf);
    DPP_ADD(x, 0x142, 0xa);
    return x;
}

__global__ __launch_bounds__(256) void render_composite_kernel(
    const float* __restrict__ density,   // [B, N]
    const float* __restrict__ deltas,    // [B, N]
    const float* __restrict__ zs,        // [B, N]
    const float* __restrict__ rgbs,      // [B, N, 3]
    const float* __restrict__ normals,   // [B, N, 3]
    float* __restrict__ out)             // [B, 8]
{
    const int tid  = threadIdx.x;
    const int lane = tid & 63;
    const int k    = lane & 31;              // lane within ray
    const int ray  = blockIdx.x * 8 + (tid >> 6) * 2 + (lane >> 5);

    const size_t row  = (size_t)ray * NS;
    const size_t row3 = (size_t)ray * NS * 3;

    // ---- issue all loads up front (independent) ----
    const float4 d  = reinterpret_cast<const float4*>(density + row)[k];
    const float4 dl = reinterpret_cast<const float4*>(deltas  + row)[k];
    const float4 z  = reinterpret_cast<const float4*>(zs      + row)[k];

    const float4* rg = reinterpret_cast<const float4*>(rgbs    + row3) + k * 3;
    const float4* nm = reinterpret_cast<const float4*>(normals + row3) + k * 3;
    const float4 r0 = rg[0], r1 = rg[1], r2 = rg[2];
    const float4 n0 = nm[0], n1 = nm[1], n2 = nm[2];

    // ---- per-lane sigma*delta for 4 samples ----
    const float s0 = d.x * dl.x;
    const float s1 = d.y * dl.y;
    const float s2 = d.z * dl.z;
    const float s3 = d.w * dl.w;
    const float slocal = (s0 + s1) + (s2 + s3);

    // ---- 32-lane inclusive DPP scan -> exclusive base ----
    const float prefix = scan32(slocal);
    const float S0 = prefix - slocal;
    const float S1 = S0 + s0;
    const float S2 = S1 + s1;
    const float S3 = S2 + s2;
    const float S4 = S3 + s3;

    const float e0 = __expf(-S0);
    const float e1 = __expf(-S1);
    const float e2 = __expf(-S2);
    const float e3 = __expf(-S3);
    const float e4 = __expf(-S4);
    const float w0 = e0 - e1;
    const float w1 = e1 - e2;
    const float w2 = e2 - e3;
    const float w3 = e3 - e4;

    // ---- per-lane weighted partials ----
    // sample->color layout in r0..r2 (12 floats = 4 samples x rgb):
    //   s0: r0.x r0.y r0.z | s1: r0.w r1.x r1.y | s2: r1.z r1.w r2.x | s3: r2.y r2.z r2.w
    float acc_r  = w0 * r0.x + w1 * r0.w + w2 * r1.z + w3 * r2.y;
    float acc_g  = w0 * r0.y + w1 * r1.x + w2 * r1.w + w3 * r2.z;
    float acc_b  = w0 * r0.z + w1 * r1.y + w2 * r2.x + w3 * r2.w;
    float acc_nr = w0 * n0.x + w1 * n0.w + w2 * n1.z + w3 * n2.y;
    float acc_ng = w0 * n0.y + w1 * n1.x + w2 * n1.w + w3 * n2.z;
    float acc_nb = w0 * n0.z + w1 * n1.y + w2 * n2.x + w3 * n2.w;
    float acc_w  = (w0 + w1) + (w2 + w3);
    float acc_wz = w0 * z.x + w1 * z.y + w2 * z.z + w3 * z.w;

    // ---- 32-lane DPP reductions (inclusive scan; lane 31 of each half = total) ----
    acc_r  = scan32(acc_r);
    acc_g  = scan32(acc_g);
    acc_b  = scan32(acc_b);
    acc_nr = scan32(acc_nr);
    acc_ng = scan32(acc_ng);
    acc_nb = scan32(acc_nb);
    acc_w  = scan32(acc_w);
    acc_wz = scan32(acc_wz);

    if (k == 31) {
        const float depth = acc_wz / (acc_w + 1e-8f);
        float4* o = reinterpret_cast<float4*>(out + (size_t)ray * 8);
        o[0] = make_float4(acc_r, acc_g, acc_b, depth);
        o[1] = make_float4(acc_nr, acc_ng, acc_nb, acc_w);
    }
}

extern "C" void kernel_launch(void* const* d_in, const int* in_sizes, int n_in,
                              void* d_out, int out_size, void* d_ws, size_t ws_size,
                              hipStream_t stream) {
    const float* density = (const float*)d_in[0];
    const float* deltas  = (const float*)d_in[1];
    const float* zs      = (const float*)d_in[2];
    const float* rgbs    = (const float*)d_in[3];
    const float* normals = (const float*)d_in[4];
    float* out = (float*)d_out;

    // 256 threads = 4 waves = 8 rays per block
    const int grid = RAYS / 8;                          // 8192 blocks
    render_composite_kernel<<<grid, 256, 0, stream>>>(
        density, deltas, zs, rgbs, normals, out);
}